// Round 1
// baseline (576.152 us; speedup 1.0000x reference)
//
#include <hip/hip_runtime.h>

#define BATCH 8
#define SEQ   2048
#define EMB   1024
#define HD    64
#define HEADS 16

// ---------------- QKV projection ----------------
// y[r, d] = sum_e x[r, e] * W[d, e]   (Linear without bias: x @ W^T)
// grid: (M/64, 3) ; block 256 (16x16 threads, 4x4 outputs each)
__global__ __launch_bounds__(256) void qkv_kernel(
    const float* __restrict__ x, const float* __restrict__ Wq,
    const float* __restrict__ Wk, const float* __restrict__ Wv,
    float* __restrict__ q, float* __restrict__ k, float* __restrict__ v)
{
    __shared__ float xs[32][65];   // [e][row], +1 pad -> conflict-free
    __shared__ float ws[32][65];   // [e][col]
    const float* W;
    float* y;
    if (blockIdx.y == 0)      { W = Wq; y = q; }
    else if (blockIdx.y == 1) { W = Wk; y = k; }
    else                      { W = Wv; y = v; }

    const int t  = threadIdx.x;
    const int ty = t >> 4, tx = t & 15;
    const int row0 = blockIdx.x * 64;

    float acc[4][4] = {};
    for (int e0 = 0; e0 < EMB; e0 += 32) {
        #pragma unroll
        for (int i = 0; i < 8; ++i) {
            int lin = i * 256 + t;
            int r = lin >> 5, c = lin & 31;          // coalesced on c (contig e)
            xs[c][r] = x[(size_t)(row0 + r) * EMB + e0 + c];
            ws[c][r] = W[(size_t)r * EMB + e0 + c];  // r is output col d here
        }
        __syncthreads();
        #pragma unroll 8
        for (int kk = 0; kk < 32; ++kk) {
            float a[4], bb[4];
            #pragma unroll
            for (int i = 0; i < 4; ++i) a[i]  = xs[kk][4 * ty + i];
            #pragma unroll
            for (int j = 0; j < 4; ++j) bb[j] = ws[kk][4 * tx + j];
            #pragma unroll
            for (int i = 0; i < 4; ++i)
                #pragma unroll
                for (int j = 0; j < 4; ++j)
                    acc[i][j] += a[i] * bb[j];
        }
        __syncthreads();
    }
    #pragma unroll
    for (int i = 0; i < 4; ++i) {
        float4 val = make_float4(acc[i][0], acc[i][1], acc[i][2], acc[i][3]);
        *(float4*)&y[(size_t)(row0 + 4 * ty + i) * HD + 4 * tx] = val;
    }
}

// ---------------- Column-softmax denominators ----------------
// l_inv[b, c] = 1 / sum_i exp(q[b,i,:] . k[b,c,:])
// No max subtraction needed: |scores| <~ 50 << 88 (f32 exp range).
// grid: (SEQ/64 col tiles, BATCH) ; block 256 (16x16, 4 rows x 4 cols each)
__global__ __launch_bounds__(256) void stats_kernel(
    const float* __restrict__ q, const float* __restrict__ k,
    float* __restrict__ l_inv)
{
    __shared__ float ks[64][65];   // [col][e]
    __shared__ float qs[64][65];   // [row][e]
    __shared__ float red[16][64];
    const int b  = blockIdx.y;
    const int c0 = blockIdx.x * 64;
    const int t  = threadIdx.x;
    const int ty = t >> 4, tx = t & 15;

    #pragma unroll
    for (int i = 0; i < 16; ++i) {
        int lin = i * 256 + t;
        int col = lin >> 6, e = lin & 63;
        ks[col][e] = k[((size_t)b * SEQ + c0 + col) * HD + e];
    }

    float psum[4] = {0.f, 0.f, 0.f, 0.f};
    for (int r0 = 0; r0 < SEQ; r0 += 64) {
        __syncthreads();   // guards ks (iter 0) and qs reuse
        #pragma unroll
        for (int i = 0; i < 16; ++i) {
            int lin = i * 256 + t;
            int rr = lin >> 6, e = lin & 63;
            qs[rr][e] = q[((size_t)b * SEQ + r0 + rr) * HD + e];
        }
        __syncthreads();
        float s[4][4] = {};
        #pragma unroll 8
        for (int e = 0; e < 64; ++e) {
            float a[4], bb[4];
            #pragma unroll
            for (int i = 0; i < 4; ++i) a[i]  = qs[4 * ty + i][e];
            #pragma unroll
            for (int j = 0; j < 4; ++j) bb[j] = ks[4 * tx + j][e];
            #pragma unroll
            for (int i = 0; i < 4; ++i)
                #pragma unroll
                for (int j = 0; j < 4; ++j)
                    s[i][j] += a[i] * bb[j];
        }
        #pragma unroll
        for (int j = 0; j < 4; ++j)
            #pragma unroll
            for (int i = 0; i < 4; ++i)
                psum[j] += __expf(s[i][j]);
    }

    #pragma unroll
    for (int j = 0; j < 4; ++j) red[ty][4 * tx + j] = psum[j];
    __syncthreads();
    if (t < 64) {
        float sum = 0.f;
        #pragma unroll
        for (int i = 0; i < 16; ++i) sum += red[i][t];
        l_inv[(size_t)b * SEQ + c0 + t] = 1.0f / sum;
    }
}

// ---------------- Output: out = exp(scores) @ (v * l_inv), tiled x16 heads ----
// grid: (SEQ/64 row tiles, BATCH) ; block 256 (16x16, 4x4 each)
__global__ __launch_bounds__(256) void out_kernel(
    const float* __restrict__ q, const float* __restrict__ k,
    const float* __restrict__ v, const float* __restrict__ l_inv,
    float* __restrict__ out)
{
    __shared__ float qs[64][65];   // [row][e]
    __shared__ float ks[64][65];   // [col][e]
    __shared__ float vs[64][65];   // [col][d], pre-scaled by l_inv
    __shared__ float ps[64][65];   // exp(scores) [row][col]
    const int b  = blockIdx.y;
    const int r0 = blockIdx.x * 64;
    const int t  = threadIdx.x;
    const int ty = t >> 4, tx = t & 15;

    #pragma unroll
    for (int i = 0; i < 16; ++i) {
        int lin = i * 256 + t;
        int rr = lin >> 6, e = lin & 63;
        qs[rr][e] = q[((size_t)b * SEQ + r0 + rr) * HD + e];
    }

    float o[4][4] = {};
    for (int c0 = 0; c0 < SEQ; c0 += 64) {
        __syncthreads();   // guards qs (iter 0) and ks/vs/ps reuse
        #pragma unroll
        for (int i = 0; i < 16; ++i) {
            int lin = i * 256 + t;
            int col = lin >> 6, e = lin & 63;
            size_t gc = (size_t)b * SEQ + c0 + col;
            ks[col][e] = k[gc * HD + e];
            vs[col][e] = v[gc * HD + e] * l_inv[gc];
        }
        __syncthreads();
        // scores tile
        float s[4][4] = {};
        #pragma unroll 8
        for (int e = 0; e < 64; ++e) {
            float a[4], bb[4];
            #pragma unroll
            for (int i = 0; i < 4; ++i) a[i]  = qs[4 * ty + i][e];
            #pragma unroll
            for (int j = 0; j < 4; ++j) bb[j] = ks[4 * tx + j][e];
            #pragma unroll
            for (int i = 0; i < 4; ++i)
                #pragma unroll
                for (int j = 0; j < 4; ++j)
                    s[i][j] += a[i] * bb[j];
        }
        // exp -> shared
        #pragma unroll
        for (int i = 0; i < 4; ++i)
            #pragma unroll
            for (int j = 0; j < 4; ++j)
                ps[4 * ty + i][4 * tx + j] = __expf(s[i][j]);
        __syncthreads();
        // PV accumulate
        #pragma unroll 8
        for (int col = 0; col < 64; ++col) {
            float p[4], vv[4];
            #pragma unroll
            for (int i = 0; i < 4; ++i) p[i]  = ps[4 * ty + i][col];
            #pragma unroll
            for (int j = 0; j < 4; ++j) vv[j] = vs[col][4 * tx + j];
            #pragma unroll
            for (int i = 0; i < 4; ++i)
                #pragma unroll
                for (int j = 0; j < 4; ++j)
                    o[i][j] += p[i] * vv[j];
        }
    }

    // epilogue: write the same 64-wide head output to all 16 head slots
    #pragma unroll
    for (int i = 0; i < 4; ++i) {
        float4 val = make_float4(o[i][0], o[i][1], o[i][2], o[i][3]);
        size_t rowoff = ((size_t)b * SEQ + r0 + 4 * ty + i) * (HD * HEADS);
        #pragma unroll
        for (int h = 0; h < HEADS; ++h) {
            *(float4*)(out + rowoff + h * HD + 4 * tx) = val;
        }
    }
}

extern "C" void kernel_launch(void* const* d_in, const int* in_sizes, int n_in,
                              void* d_out, int out_size, void* d_ws, size_t ws_size,
                              hipStream_t stream)
{
    const float* x  = (const float*)d_in[0];
    const float* Wq = (const float*)d_in[1];
    const float* Wk = (const float*)d_in[2];
    const float* Wv = (const float*)d_in[3];
    float* out = (float*)d_out;

    float* ws    = (float*)d_ws;
    const size_t NQ = (size_t)BATCH * SEQ * HD;   // 1,048,576
    float* q     = ws;
    float* k     = ws + NQ;
    float* v     = ws + 2 * NQ;
    float* l_inv = ws + 3 * NQ;                   // + 16384 -> ~12.1 MB total

    qkv_kernel<<<dim3(BATCH * SEQ / 64, 3), 256, 0, stream>>>(x, Wq, Wk, Wv, q, k, v);
    stats_kernel<<<dim3(SEQ / 64, BATCH), 256, 0, stream>>>(q, k, l_inv);
    out_kernel<<<dim3(SEQ / 64, BATCH), 256, 0, stream>>>(q, k, v, l_inv, out);
}

// Round 2
// 227.642 us; speedup vs baseline: 2.5310x; 2.5310x over previous
//
#include <hip/hip_runtime.h>

#define BATCH 8
#define SEQ   2048
#define EMB   1024
#define HD    64
#define HEADS 16

typedef _Float16 half8 __attribute__((ext_vector_type(8)));
typedef short    short8 __attribute__((ext_vector_type(8)));
typedef float    f32x4 __attribute__((ext_vector_type(4)));

// f32 -> bf16 bits, round-to-nearest-even
__device__ __forceinline__ short f2bf(float f) {
    union { float f; unsigned u; } x; x.f = f;
    unsigned r = x.u + 0x7fffu + ((x.u >> 16) & 1u);
    return (short)(r >> 16);
}

// load 8 consecutive f32, convert to 8 fp16
__device__ __forceinline__ half8 cvt8(const float* __restrict__ src) {
    float4 f0 = *(const float4*)src;
    float4 f1 = *(const float4*)(src + 4);
    half8 h;
    h[0] = (_Float16)f0.x; h[1] = (_Float16)f0.y; h[2] = (_Float16)f0.z; h[3] = (_Float16)f0.w;
    h[4] = (_Float16)f1.x; h[5] = (_Float16)f1.y; h[6] = (_Float16)f1.z; h[7] = (_Float16)f1.w;
    return h;
}

// ---------------- QKV projection (fp16 MFMA) ----------------
// q/k/v[r,d] = sum_e x[r,e] * W[d,e].  64 rows/block, 512 thr = 8 waves.
// wave: strip=(w&3) -> 16 rows; half=(w>>2) -> 6 of the 12 (matrix,ntile) ctiles.
__global__ __launch_bounds__(512) void qkv_kernel(
    const float* __restrict__ x, const float* __restrict__ Wq,
    const float* __restrict__ Wk, const float* __restrict__ Wv,
    _Float16* __restrict__ qh, _Float16* __restrict__ kh, float* __restrict__ vf)
{
    __shared__ _Float16 xs[64][72];       // [row][e] fp16, 16B-aligned rows (144B)
    __shared__ _Float16 wsb[3][64][72];   // [m][d][e]
    const int t = threadIdx.x;
    const int lane = t & 63, wave = t >> 6;
    const int strip = wave & 3, half = wave >> 2;
    const int l15 = lane & 15, quad = lane >> 4;
    const int row0 = blockIdx.x * 64;
    const float* const Wm[3] = { Wq, Wk, Wv };

    f32x4 acc[6] = {};
    const int srow = t >> 3, sc8 = t & 7;   // staging: 8 halves/thread per 4096-half tile

    for (int k0 = 0; k0 < EMB; k0 += 64) {
        *(half8*)&xs[srow][sc8 * 8] = cvt8(&x[(size_t)(row0 + srow) * EMB + k0 + sc8 * 8]);
        #pragma unroll
        for (int m = 0; m < 3; ++m)
            *(half8*)&wsb[m][srow][sc8 * 8] = cvt8(&Wm[m][(size_t)srow * EMB + k0 + sc8 * 8]);
        __syncthreads();
        #pragma unroll
        for (int kc = 0; kc < 2; ++kc) {
            half8 a = *(half8*)&xs[strip * 16 + l15][kc * 32 + quad * 8];
            #pragma unroll
            for (int j = 0; j < 6; ++j) {
                int cidx = half * 6 + j, m = cidx >> 2, n = cidx & 3;
                half8 b = *(half8*)&wsb[m][n * 16 + l15][kc * 32 + quad * 8];
                acc[j] = __builtin_amdgcn_mfma_f32_16x16x32_f16(a, b, acc[j], 0, 0, 0);
            }
        }
        __syncthreads();
    }
    #pragma unroll
    for (int j = 0; j < 6; ++j) {
        int cidx = half * 6 + j, m = cidx >> 2, n = cidx & 3;
        int col = n * 16 + l15;
        #pragma unroll
        for (int r = 0; r < 4; ++r) {
            size_t rowg = row0 + strip * 16 + quad * 4 + r;
            float v = acc[j][r];
            if (m == 0)      qh[rowg * HD + col] = (_Float16)v;
            else if (m == 1) kh[rowg * HD + col] = (_Float16)v;
            else             vf[rowg * HD + col] = v;
        }
    }
}

// ---------------- Column-softmax denominators (fp16 MFMA) ----------------
// l_inv[b,c] = 1 / sum_i exp(q[b,i,:] . k[b,c,:]).  |s|<~50 so f32 exp is safe.
// 32 keys/block; 4 waves each take query strip w*16, step 64, over all 2048 rows.
__global__ __launch_bounds__(256) void stats_kernel(
    const _Float16* __restrict__ qh, const _Float16* __restrict__ kh,
    float* __restrict__ l_inv)
{
    __shared__ _Float16 ks_s[32][72];
    __shared__ _Float16 qs_s[64][72];
    __shared__ float red[4][32];
    const int t = threadIdx.x;
    const int lane = t & 63, wave = t >> 6;
    const int l15 = lane & 15, quad = lane >> 4;
    const int b = blockIdx.y, c0 = blockIdx.x * 32;

    {   // stage k tile once: 2048 halves, 8/thread
        int row = t >> 3, c8 = t & 7;
        *(half8*)&ks_s[row][c8 * 8] =
            *(const half8*)&kh[((size_t)b * SEQ + c0 + row) * HD + c8 * 8];
    }
    __syncthreads();
    half8 bfrag[2][2];   // hoisted B fragments (keys fixed for whole sweep)
    #pragma unroll
    for (int c = 0; c < 2; ++c)
        #pragma unroll
        for (int kc = 0; kc < 2; ++kc)
            bfrag[c][kc] = *(half8*)&ks_s[c * 16 + l15][kc * 32 + quad * 8];

    float csum[2] = { 0.f, 0.f };
    for (int r0 = 0; r0 < SEQ; r0 += 64) {
        #pragma unroll
        for (int i = 0; i < 2; ++i) {   // stage 64 q rows: 4096 halves
            int cid = i * 256 + t, row = cid >> 3, c8 = cid & 7;
            *(half8*)&qs_s[row][c8 * 8] =
                *(const half8*)&qh[((size_t)b * SEQ + r0 + row) * HD + c8 * 8];
        }
        __syncthreads();
        f32x4 s[2] = {};
        #pragma unroll
        for (int kc = 0; kc < 2; ++kc) {
            half8 a = *(half8*)&qs_s[wave * 16 + l15][kc * 32 + quad * 8];
            #pragma unroll
            for (int c = 0; c < 2; ++c)
                s[c] = __builtin_amdgcn_mfma_f32_16x16x32_f16(a, bfrag[c][kc], s[c], 0, 0, 0);
        }
        #pragma unroll
        for (int c = 0; c < 2; ++c)
            #pragma unroll
            for (int r = 0; r < 4; ++r)
                csum[c] += __expf(s[c][r]);
        __syncthreads();
    }
    #pragma unroll
    for (int c = 0; c < 2; ++c) {   // reduce over the 4 quads (rows) in-wave
        csum[c] += __shfl_xor(csum[c], 16);
        csum[c] += __shfl_xor(csum[c], 32);
    }
    if (lane < 16) { red[wave][l15] = csum[0]; red[wave][16 + l15] = csum[1]; }
    __syncthreads();
    if (t < 32) {
        float sum = red[0][t] + red[1][t] + red[2][t] + red[3][t];
        l_inv[(size_t)b * SEQ + c0 + t] = 1.0f / sum;
    }
}

// ---------------- out = exp(S) @ (v * l_inv), fp16 scores + bf16 PV ----------
// 32 q-rows/block (512 blocks). wave: strip=(w&1) q-rows, kh=(w>>1) key half.
__global__ __launch_bounds__(256) void out_kernel(
    const _Float16* __restrict__ qh, const _Float16* __restrict__ kh,
    const float* __restrict__ vf, const float* __restrict__ l_inv,
    float* __restrict__ out)
{
    __shared__ _Float16 qs[32][72];     // [row][e]
    __shared__ _Float16 ks[64][72];     // [key][e]
    __shared__ short    vst[64][72];    // transposed, bf16: [d][key], v*l_inv
    __shared__ short    ps[32][72];     // bf16 exp(S): [row][key]  (wave-private quadrants)
    __shared__ float    ored[2][16][72];// cross-wave (key-half) partial sums
    __shared__ float    otile[32][72];  // final f32 tile for vectorized epilogue
    const int t = threadIdx.x;
    const int lane = t & 63, wave = t >> 6;
    const int strip = wave & 1, khf = wave >> 1;
    const int l15 = lane & 15, quad = lane >> 4;
    const int b = blockIdx.y, r0 = blockIdx.x * 32;

    {   // stage q rows once: 2048 halves
        int row = t >> 3, c8 = t & 7;
        *(half8*)&qs[row][c8 * 8] =
            *(const half8*)&qh[((size_t)b * SEQ + r0 + row) * HD + c8 * 8];
    }

    f32x4 oacc[4] = {};
    for (int c0 = 0; c0 < SEQ; c0 += 64) {
        __syncthreads();   // qs ready (iter 0); prev iter's reads of ks/vst/ps done
        #pragma unroll
        for (int i = 0; i < 2; ++i) {   // stage 64 keys: 4096 halves
            int cid = i * 256 + t, row = cid >> 3, c8 = cid & 7;
            *(half8*)&ks[row][c8 * 8] =
                *(const half8*)&kh[((size_t)b * SEQ + c0 + row) * HD + c8 * 8];
        }
        #pragma unroll
        for (int i = 0; i < 4; ++i) {   // stage v (f32) -> scaled bf16, transposed
            int cid = i * 256 + t, c = cid >> 4, d4 = (cid & 15) * 4;
            float4 vv = *(const float4*)&vf[((size_t)b * SEQ + c0 + c) * HD + d4];
            float sc = l_inv[(size_t)b * SEQ + c0 + c];
            vst[d4 + 0][c] = f2bf(vv.x * sc);
            vst[d4 + 1][c] = f2bf(vv.y * sc);
            vst[d4 + 2][c] = f2bf(vv.z * sc);
            vst[d4 + 3][c] = f2bf(vv.w * sc);
        }
        __syncthreads();
        // scores: 16 rows x 32 keys per wave
        f32x4 sfrag[2] = {};
        #pragma unroll
        for (int kc = 0; kc < 2; ++kc) {
            half8 a = *(half8*)&qs[strip * 16 + l15][kc * 32 + quad * 8];
            #pragma unroll
            for (int c = 0; c < 2; ++c) {
                half8 bb = *(half8*)&ks[khf * 32 + c * 16 + l15][kc * 32 + quad * 8];
                sfrag[c] = __builtin_amdgcn_mfma_f32_16x16x32_f16(a, bb, sfrag[c], 0, 0, 0);
            }
        }
        // exp -> bf16 -> LDS (C-layout -> A-layout round trip; wave-private region)
        #pragma unroll
        for (int c = 0; c < 2; ++c)
            #pragma unroll
            for (int r = 0; r < 4; ++r)
                ps[strip * 16 + quad * 4 + r][khf * 32 + c * 16 + l15] =
                    f2bf(__expf(sfrag[c][r]));
        __syncthreads();   // safety barrier before PV reads
        // PV: K=32 (this wave's key half), N=64
        short8 pa = *(short8*)&ps[strip * 16 + l15][khf * 32 + quad * 8];
        #pragma unroll
        for (int n = 0; n < 4; ++n) {
            short8 vb = *(short8*)&vst[n * 16 + l15][khf * 32 + quad * 8];
            oacc[n] = __builtin_amdgcn_mfma_f32_16x16x32_bf16(pa, vb, oacc[n], 0, 0, 0);
        }
    }

    // combine the two key-half waves per strip
    if (khf == 1) {
        #pragma unroll
        for (int n = 0; n < 4; ++n)
            #pragma unroll
            for (int r = 0; r < 4; ++r)
                ored[strip][quad * 4 + r][n * 16 + l15] = oacc[n][r];
    }
    __syncthreads();
    if (khf == 0) {
        #pragma unroll
        for (int n = 0; n < 4; ++n)
            #pragma unroll
            for (int r = 0; r < 4; ++r)
                otile[strip * 16 + quad * 4 + r][n * 16 + l15] =
                    oacc[n][r] + ored[strip][quad * 4 + r][n * 16 + l15];
    }
    __syncthreads();
    // epilogue: 32x64 f32 tile -> x16 heads, coalesced float4 stores
    {
        int row = t >> 3, seg = t & 7;
        float4 u0 = *(float4*)&otile[row][seg * 8];
        float4 u1 = *(float4*)&otile[row][seg * 8 + 4];
        size_t base = ((size_t)b * SEQ + r0 + row) * (HD * HEADS);
        #pragma unroll
        for (int h = 0; h < HEADS; ++h) {
            *(float4*)&out[base + h * HD + seg * 8]     = u0;
            *(float4*)&out[base + h * HD + seg * 8 + 4] = u1;
        }
    }
}

extern "C" void kernel_launch(void* const* d_in, const int* in_sizes, int n_in,
                              void* d_out, int out_size, void* d_ws, size_t ws_size,
                              hipStream_t stream)
{
    const float* x  = (const float*)d_in[0];
    const float* Wq = (const float*)d_in[1];
    const float* Wk = (const float*)d_in[2];
    const float* Wv = (const float*)d_in[3];
    float* out = (float*)d_out;

    const size_t N = (size_t)BATCH * SEQ * HD;   // 1,048,576
    _Float16* qh  = (_Float16*)d_ws;
    _Float16* khp = qh + N;
    float* vf     = (float*)(khp + N);
    float* l_inv  = vf + N;                      // total ~8.1 MB

    qkv_kernel<<<dim3(BATCH * SEQ / 64), 512, 0, stream>>>(x, Wq, Wk, Wv, qh, khp, vf);
    stats_kernel<<<dim3(SEQ / 32, BATCH), 256, 0, stream>>>(qh, khp, l_inv);
    out_kernel<<<dim3(SEQ / 32, BATCH), 256, 0, stream>>>(qh, khp, vf, l_inv, out);
}